// Round 1
// baseline (3182.654 us; speedup 1.0000x reference)
//
#include <hip/hip_runtime.h>
#include <cstdint>
#include <cstddef>

typedef int v4i __attribute__((ext_vector_type(4)));

#define HWSZ 3136
#define WID 56
#define CCH 256
#define BAT 32
#define NPIX (BAT*HWSZ)   /* 100352 */
#define KTOT 2304
#define PW 58
#define PIMG (PW*PW)      /* 3364 */

static __device__ __forceinline__ uint16_t f2bf(float f) {
    uint32_t x = __float_as_uint(f);
    x += 0x7fffu + ((x >> 16) & 1u);
    return (uint16_t)(x >> 16);
}

static __device__ __forceinline__ void load_lds_16(const void* g, void* l) {
    __builtin_amdgcn_global_load_lds(
        (const __attribute__((address_space(1))) uint32_t*)g,
        (__attribute__((address_space(3))) uint32_t*)l, 16, 0, 0);
}

// ---------------- pack weights + fused epilogue params ----------------
__global__ void pack_weights(const float* __restrict__ w,
                             const float* __restrict__ sc,
                             const float* __restrict__ g,
                             const float* __restrict__ bb,
                             const float* __restrict__ m,
                             const float* __restrict__ v,
                             int8_t* __restrict__ wpack,
                             float* __restrict__ params) {
    int o = blockIdx.x;
    int t = threadIdx.x;
    const float* wo = w + (size_t)o * KTOT;
    __shared__ float red[256];
    float s = 0.f;
    for (int i = t; i < KTOT; i += 256) {
        float val = wo[i];            // i = c*9 + tap
        s += fabsf(val);
        int c = i / 9, tap = i - c * 9;
        int8_t sgn = (val > 0.f) ? 1 : ((val < 0.f) ? -1 : 0);
        wpack[(size_t)o * KTOT + tap * 256 + c] = sgn;
    }
    red[t] = s;
    __syncthreads();
    for (int off = 128; off > 0; off >>= 1) {
        if (t < off) red[t] += red[t + off];
        __syncthreads();
    }
    if (t == 0) {
        float alpha = red[0] / (float)KTOT;
        float inv = rsqrtf(v[o] + 1e-5f);
        float cs = alpha * inv * g[o];
        params[o]         = cs;
        params[256 + o]   = cs * sc[o];
        params[512 + o]   = bb[o] - m[o] * inv * g[o];
    }
}

// ---------------- zero halos of 4 padded activation buffers ----------------
__global__ void halo_zero(int8_t* b0, int8_t* b1, int8_t* b2, int8_t* b3) {
    int bx = blockIdx.x;                  // 0..127 : buf = bx>>5, img = bx&31
    int8_t* bufs[4] = {b0, b1, b2, b3};
    int8_t* base = bufs[bx >> 5] + (size_t)(bx & 31) * PIMG * 256;
    v4i z = (v4i){0, 0, 0, 0};
    for (int idx = threadIdx.x; idx < 3648; idx += 256) {
        size_t off;
        if (idx < 928)       off = (size_t)idx * 16;
        else if (idx < 1856) off = (size_t)57 * PW * 256 + (size_t)(idx - 928) * 16;
        else {
            int s = idx - 1856;
            int seg = s >> 4, w16 = s & 15;
            int h = 1 + (seg >> 1);
            int w = (seg & 1) ? 57 : 0;
            off = ((size_t)h * PW + w) * 256 + (size_t)w16 * 16;
        }
        *(v4i*)(base + off) = z;
    }
}

// ---------------- binarize x (NCHW fp32) -> a1,a2 (padded NHWC int8) --------
__global__ void binarize_x(const float* __restrict__ x,
                           const float* __restrict__ sh1,
                           const float* __restrict__ sh2,
                           int8_t* __restrict__ a1,
                           int8_t* __restrict__ a2) {
    __shared__ int8_t s1[32][260];
    __shared__ int8_t s2[32][260];
    int b = blockIdx.y;
    int hw0 = blockIdx.x * 32;
    int t = threadIdx.x;
    int hw4 = (t & 7) * 4;
    int crow = t >> 3;   // 0..31
    for (int i = 0; i < 8; ++i) {
        int c = crow + 32 * i;
        float4 val = *(const float4*)(x + ((size_t)(b * CCH + c)) * HWSZ + hw0 + hw4);
        float fA = sh1[c], fB = sh2[c];
        float vv[4] = {val.x, val.y, val.z, val.w};
        for (int j = 0; j < 4; ++j) {
            float u1 = vv[j] + fA;
            float u2 = vv[j] + fB;
            s1[hw4 + j][c] = (u1 > 0.f) ? 1 : ((u1 < 0.f) ? -1 : 0);
            s2[hw4 + j][c] = (u2 > 0.f) ? 1 : ((u2 < 0.f) ? -1 : 0);
        }
    }
    __syncthreads();
    int c4 = (t & 63) * 4;
    for (int j = 0; j < 8; ++j) {
        int hwl = (t >> 6) + 4 * j;
        int hwg = hw0 + hwl;
        int h = hwg / WID, w = hwg - h * WID;
        uchar4 p1 = *(const uchar4*)&s1[hwl][c4];
        uchar4 p2 = *(const uchar4*)&s2[hwl][c4];
        size_t dst = ((size_t)(b * PIMG) + (size_t)(h + 1) * PW + (w + 1)) * 256 + c4;
        *(uchar4*)(a1 + dst) = p1;
        *(uchar4*)(a2 + dst) = p2;
    }
}

// ---------------- binarized implicit-GEMM conv ----------------
// M = NPIX, N = 256, K = 2304 (dual activation streams share B).
// Groups of 2 k64-steps per barrier (32 MFMAs/wave between barriers).
// B: global_load_lds into double-buffered 8KB LDS groups, source-side
//    swizzle kk=(cs-(row>>1))&3 (round-4-verified: 0 bank conflicts).
// A: direct per-lane global v4i loads, double-buffered in registers
//    ([group-parity][step][ms]) and issued at GROUP TOP so a full group
//    of MFMAs covers their latency.
// Barrier discipline (T3/T4): raw s_barrier + counted s_waitcnt vmcnt(8)
//    — only the 2 B global_load_lds must land before the LDS buffer swap;
//    the 8 A register-loads stay in flight across the barrier (their
//    consumers are one group later; compiler inserts counted waits).
//    sched_barrier(0) fences pin issue order: [2 B stages][8 A loads] ...
//    [vmcnt(8); s_barrier], keeping the literal count valid.
// K-step order s = dh*12 + k4*3 + dw (dw innermost -> L1 reuse of A rows).
template<int SB>
__global__ __launch_bounds__(256, 6)
void bingemm(const int8_t* __restrict__ a1g,
             const int8_t* __restrict__ a2g,
             const int8_t* __restrict__ wp,
             const float* __restrict__ params,
             const void* __restrict__ res,
             void* __restrict__ outp,
             const float* __restrict__ shA,
             const float* __restrict__ shB,
             int8_t* __restrict__ o1g,
             int8_t* __restrict__ o2g)
{
    __shared__ __align__(16) int8_t sB[2][8192];   // [buf][sub*4096 + row*64 + cs*16]

    // XCD-aware decode: each XCD owns a contiguous 1/8 M-slice (4 images)
    int fid = blockIdx.x;                 // 0..3135
    int xcd = fid & 7, slot = fid >> 3;   // slot 0..391
    int o0 = (slot & 3) * 64;
    int m0 = (xcd * 98 + (slot >> 2)) * 128;

    int t = threadIdx.x, lane = t & 63, wv = t >> 6;
    int ml = lane & 15, kc = lane >> 4;

    // per-lane A pixel byte offsets (padded NHWC), 2 M-slices
    int apix[2];
    #pragma unroll
    for (int ms = 0; ms < 2; ++ms) {
        int pix = m0 + wv * 32 + ms * 16 + ml;
        int b = pix / HWSZ, hw = pix - b * HWSZ;
        int h = hw / WID, w = hw - h * WID;
        apix[ms] = (b * PIMG + (h + 1) * PW + (w + 1)) * 256 + kc * 16;
    }
    // B staging: thread t fills LDS slot t (16B) of each 4KB sub-tile.
    // slot: row = t>>2, chunk-slot cs = t&3; source chunk kk = (cs-(row>>1))&3
    int brow = t >> 2, bcs = t & 3;
    int bkk = (bcs - (brow >> 1)) & 3;
    const int8_t* bsrc = wp + (size_t)(o0 + brow) * KTOT + (size_t)bkk * 16;
    // per-lane swizzled B read base: row=ns*16+ml, cs=(kc+(ml>>1))&3
    int rbase = ml * 64 + (((kc + (ml >> 1)) & 3) * 16);

    v4i acc1[2][4], acc2[2][4];
    #pragma unroll
    for (int i = 0; i < 2; ++i)
        #pragma unroll
        for (int n = 0; n < 4; ++n) {
            acc1[i][n] = (v4i){0, 0, 0, 0};
            acc2[i][n] = (v4i){0, 0, 0, 0};
        }

    v4i a1f[2][2][2], a2f[2][2][2];   // [group-parity][step j][ms]

    // step s -> (dh, k4, dw): s = dh*12 + k4*3 + dw
    #define AOFF(s) ((((s)/12 - 1) * PW + ((s)%3 - 1)) * 256 + (((s)%12)/3) * 64)
    #define KOFF(s) ((((s)/12) * 3 + (s)%3) * 256 + (((s)%12)/3) * 64)

    // prologue: stage group 0 (B steps 0,1 into buf 0; A steps 0,1 into parity 0)
    load_lds_16(bsrc + KOFF(0), &sB[0][0 * 4096 + wv * 1024]);
    load_lds_16(bsrc + KOFF(1), &sB[0][1 * 4096 + wv * 1024]);
    __builtin_amdgcn_sched_barrier(0);
    a1f[0][0][0] = *(const v4i*)(a1g + apix[0] + AOFF(0));
    a1f[0][0][1] = *(const v4i*)(a1g + apix[1] + AOFF(0));
    a2f[0][0][0] = *(const v4i*)(a2g + apix[0] + AOFF(0));
    a2f[0][0][1] = *(const v4i*)(a2g + apix[1] + AOFF(0));
    a1f[0][1][0] = *(const v4i*)(a1g + apix[0] + AOFF(1));
    a1f[0][1][1] = *(const v4i*)(a1g + apix[1] + AOFF(1));
    a2f[0][1][0] = *(const v4i*)(a2g + apix[0] + AOFF(1));
    a2f[0][1][1] = *(const v4i*)(a2g + apix[1] + AOFF(1));
    __builtin_amdgcn_sched_barrier(0);
    asm volatile("s_waitcnt vmcnt(8)");
    __builtin_amdgcn_s_barrier();
    __builtin_amdgcn_sched_barrier(0);

    #pragma unroll
    for (int g = 0; g < 18; ++g) {
        const int gb = g & 1;
        // group top: prefetch next group's B (LDS) and A (registers).
        if (g < 17) {
            load_lds_16(bsrc + KOFF(2 * g + 2), &sB[gb ^ 1][0 * 4096 + wv * 1024]);
            load_lds_16(bsrc + KOFF(2 * g + 3), &sB[gb ^ 1][1 * 4096 + wv * 1024]);
            __builtin_amdgcn_sched_barrier(0);   // keep B stages oldest in vmcnt queue
            #pragma unroll
            for (int j = 0; j < 2; ++j) {
                const int sn = 2 * g + 2 + j;
                a1f[gb ^ 1][j][0] = *(const v4i*)(a1g + apix[0] + AOFF(sn));
                a1f[gb ^ 1][j][1] = *(const v4i*)(a1g + apix[1] + AOFF(sn));
                a2f[gb ^ 1][j][0] = *(const v4i*)(a2g + apix[0] + AOFF(sn));
                a2f[gb ^ 1][j][1] = *(const v4i*)(a2g + apix[1] + AOFF(sn));
            }
        }
        // compute current group from sB[gb] and a?f[gb]
        #pragma unroll
        for (int j = 0; j < 2; ++j) {
            v4i bf[4];
            #pragma unroll
            for (int ns = 0; ns < 4; ++ns)
                bf[ns] = *(const v4i*)&sB[gb][j * 4096 + ns * 1024 + rbase];
            #pragma unroll
            for (int ms = 0; ms < 2; ++ms)
                #pragma unroll
                for (int ns = 0; ns < 4; ++ns) {
                    acc1[ms][ns] = __builtin_amdgcn_mfma_i32_16x16x64_i8(a1f[gb][j][ms], bf[ns], acc1[ms][ns], 0, 0, 0);
                    acc2[ms][ns] = __builtin_amdgcn_mfma_i32_16x16x64_i8(a2f[gb][j][ms], bf[ns], acc2[ms][ns], 0, 0, 0);
                }
        }
        if (g < 17) {
            // counted drain: only the 2 B stages must have landed (oldest in
            // queue -> vmcnt(8) leaves the 8 A loads in flight across barrier)
            __builtin_amdgcn_sched_barrier(0);
            asm volatile("s_waitcnt vmcnt(8)");
            __builtin_amdgcn_s_barrier();
            __builtin_amdgcn_sched_barrier(0);
        }
    }
    #undef AOFF
    #undef KOFF

    // --- epilogue: D layout col(n)=lane&15, row(m)=(lane>>4)*4+r ---
    #pragma unroll
    for (int ns = 0; ns < 4; ++ns) {
        int o = o0 + ns * 16 + ml;
        float c1 = params[o], c2 = params[256 + o], c3 = params[512 + o];
        float sA = 0.f, sBv = 0.f;
        if (SB == 1) { sA = shA[o]; sBv = shB[o]; }
        #pragma unroll
        for (int ms = 0; ms < 2; ++ms) {
            int pix0 = m0 + wv * 32 + ms * 16 + kc * 4;
            int b = pix0 / HWSZ, hw = pix0 - b * HWSZ;
            size_t rb = ((size_t)(b * CCH + o)) * HWSZ + hw;
            float rv[4];
            if (SB == 1) {
                float4 r4 = *(const float4*)((const float*)res + rb);
                rv[0] = r4.x; rv[1] = r4.y; rv[2] = r4.z; rv[3] = r4.w;
            } else {
                ushort4 u = *(const ushort4*)((const uint16_t*)res + rb);
                rv[0] = __uint_as_float((uint32_t)u.x << 16);
                rv[1] = __uint_as_float((uint32_t)u.y << 16);
                rv[2] = __uint_as_float((uint32_t)u.z << 16);
                rv[3] = __uint_as_float((uint32_t)u.w << 16);
            }
            float vals[4];
            #pragma unroll
            for (int r = 0; r < 4; ++r) {
                float v = (float)acc1[ms][ns][r] * c1
                        + (float)acc2[ms][ns][r] * c2 + c3 + rv[r];
                vals[r] = fminf(1.f, fmaxf(-1.f, v));
            }
            if (SB == 1) {
                ushort4 st;
                st.x = f2bf(vals[0]); st.y = f2bf(vals[1]);
                st.z = f2bf(vals[2]); st.w = f2bf(vals[3]);
                *(ushort4*)((uint16_t*)outp + rb) = st;
                int h = hw / WID, w = hw - h * WID;
                size_t pp = ((size_t)(b * PIMG) + (size_t)(h + 1) * PW + (w + 1)) * 256 + o;
                #pragma unroll
                for (int r = 0; r < 4; ++r) {
                    float u1 = vals[r] + sA, u2 = vals[r] + sBv;
                    o1g[pp + (size_t)r * 256] = (u1 > 0.f) ? 1 : ((u1 < 0.f) ? -1 : 0);
                    o2g[pp + (size_t)r * 256] = (u2 > 0.f) ? 1 : ((u2 < 0.f) ? -1 : 0);
                }
            } else {
                float4 st = {vals[0], vals[1], vals[2], vals[3]};
                *(float4*)((float*)outp + rb) = st;
            }
        }
    }
}

extern "C" void kernel_launch(void* const* d_in, const int* in_sizes, int n_in,
                              void* d_out, int out_size, void* d_ws, size_t ws_size,
                              hipStream_t stream) {
    const float* x    = (const float*)d_in[0];
    const float* sh11 = (const float*)d_in[1];
    const float* sh12 = (const float*)d_in[2];
    const float* w1   = (const float*)d_in[3];
    const float* sc1  = (const float*)d_in[4];
    const float* g1   = (const float*)d_in[5];
    const float* b1p  = (const float*)d_in[6];
    const float* m1   = (const float*)d_in[7];
    const float* v1   = (const float*)d_in[8];
    const float* sh21 = (const float*)d_in[9];
    const float* sh22 = (const float*)d_in[10];
    const float* w2   = (const float*)d_in[11];
    const float* sc2  = (const float*)d_in[12];
    const float* g2   = (const float*)d_in[13];
    const float* b2p  = (const float*)d_in[14];
    const float* m2   = (const float*)d_in[15];
    const float* v2   = (const float*)d_in[16];

    uint8_t* ws = (uint8_t*)d_ws;
    size_t off = 0;
    auto alloc = [&](size_t bytes) -> uint8_t* {
        uint8_t* p = ws + off;
        off += (bytes + 255) & ~(size_t)255;
        return p;
    };
    const size_t PADB = (size_t)BAT * PIMG * 256;   // 27.56 MB
    int8_t*   a1  = (int8_t*)alloc(PADB);
    int8_t*   a2  = (int8_t*)alloc(PADB);
    int8_t*   bb1 = (int8_t*)alloc(PADB);
    int8_t*   bb2 = (int8_t*)alloc(PADB);
    uint16_t* mid = (uint16_t*)alloc((size_t)NPIX * 256 * 2);  // bf16 NCHW
    int8_t*   wp1 = (int8_t*)alloc((size_t)256 * KTOT);
    int8_t*   wp2 = (int8_t*)alloc((size_t)256 * KTOT);
    float*    par1 = (float*)alloc(3 * 256 * 4);
    float*    par2 = (float*)alloc(3 * 256 * 4);
    (void)ws_size; (void)in_sizes; (void)n_in; (void)out_size;

    pack_weights<<<256, 256, 0, stream>>>(w1, sc1, g1, b1p, m1, v1, wp1, par1);
    pack_weights<<<256, 256, 0, stream>>>(w2, sc2, g2, b2p, m2, v2, wp2, par2);
    halo_zero<<<128, 256, 0, stream>>>(a1, a2, bb1, bb2);
    binarize_x<<<dim3(98, 32), 256, 0, stream>>>(x, sh11, sh12, a1, a2);
    bingemm<1><<<3136, 256, 0, stream>>>(a1, a2, wp1, par1, x, mid,
                                         sh21, sh22, bb1, bb2);
    bingemm<2><<<3136, 256, 0, stream>>>(bb1, bb2, wp2, par2, mid, d_out,
                                         nullptr, nullptr, nullptr, nullptr);
}

// Round 2
// 726.870 us; speedup vs baseline: 4.3786x; 4.3786x over previous
//
#include <hip/hip_runtime.h>
#include <cstdint>
#include <cstddef>

typedef int v4i __attribute__((ext_vector_type(4)));

#define HWSZ 3136
#define WID 56
#define CCH 256
#define BAT 32
#define NPIX (BAT*HWSZ)   /* 100352 */
#define KTOT 2304
#define PW 58
#define PIMG (PW*PW)      /* 3364 */

static __device__ __forceinline__ uint16_t f2bf(float f) {
    uint32_t x = __float_as_uint(f);
    x += 0x7fffu + ((x >> 16) & 1u);
    return (uint16_t)(x >> 16);
}

static __device__ __forceinline__ void load_lds_16(const void* g, void* l) {
    __builtin_amdgcn_global_load_lds(
        (const __attribute__((address_space(1))) uint32_t*)g,
        (__attribute__((address_space(3))) uint32_t*)l, 16, 0, 0);
}

// ---------------- pack weights + fused epilogue params ----------------
__global__ void pack_weights(const float* __restrict__ w,
                             const float* __restrict__ sc,
                             const float* __restrict__ g,
                             const float* __restrict__ bb,
                             const float* __restrict__ m,
                             const float* __restrict__ v,
                             int8_t* __restrict__ wpack,
                             float* __restrict__ params) {
    int o = blockIdx.x;
    int t = threadIdx.x;
    const float* wo = w + (size_t)o * KTOT;
    __shared__ float red[256];
    float s = 0.f;
    for (int i = t; i < KTOT; i += 256) {
        float val = wo[i];            // i = c*9 + tap
        s += fabsf(val);
        int c = i / 9, tap = i - c * 9;
        int8_t sgn = (val > 0.f) ? 1 : ((val < 0.f) ? -1 : 0);
        wpack[(size_t)o * KTOT + tap * 256 + c] = sgn;
    }
    red[t] = s;
    __syncthreads();
    for (int off = 128; off > 0; off >>= 1) {
        if (t < off) red[t] += red[t + off];
        __syncthreads();
    }
    if (t == 0) {
        float alpha = red[0] / (float)KTOT;
        float inv = rsqrtf(v[o] + 1e-5f);
        float cs = alpha * inv * g[o];
        params[o]         = cs;
        params[256 + o]   = cs * sc[o];
        params[512 + o]   = bb[o] - m[o] * inv * g[o];
    }
}

// ---------------- zero halos of 4 padded activation buffers ----------------
__global__ void halo_zero(int8_t* b0, int8_t* b1, int8_t* b2, int8_t* b3) {
    int bx = blockIdx.x;                  // 0..127 : buf = bx>>5, img = bx&31
    int8_t* bufs[4] = {b0, b1, b2, b3};
    int8_t* base = bufs[bx >> 5] + (size_t)(bx & 31) * PIMG * 256;
    v4i z = (v4i){0, 0, 0, 0};
    for (int idx = threadIdx.x; idx < 3648; idx += 256) {
        size_t off;
        if (idx < 928)       off = (size_t)idx * 16;
        else if (idx < 1856) off = (size_t)57 * PW * 256 + (size_t)(idx - 928) * 16;
        else {
            int s = idx - 1856;
            int seg = s >> 4, w16 = s & 15;
            int h = 1 + (seg >> 1);
            int w = (seg & 1) ? 57 : 0;
            off = ((size_t)h * PW + w) * 256 + (size_t)w16 * 16;
        }
        *(v4i*)(base + off) = z;
    }
}

// ---------------- binarize x (NCHW fp32) -> a1,a2 (padded NHWC int8) --------
__global__ void binarize_x(const float* __restrict__ x,
                           const float* __restrict__ sh1,
                           const float* __restrict__ sh2,
                           int8_t* __restrict__ a1,
                           int8_t* __restrict__ a2) {
    __shared__ int8_t s1[32][260];
    __shared__ int8_t s2[32][260];
    int b = blockIdx.y;
    int hw0 = blockIdx.x * 32;
    int t = threadIdx.x;
    int hw4 = (t & 7) * 4;
    int crow = t >> 3;   // 0..31
    for (int i = 0; i < 8; ++i) {
        int c = crow + 32 * i;
        float4 val = *(const float4*)(x + ((size_t)(b * CCH + c)) * HWSZ + hw0 + hw4);
        float fA = sh1[c], fB = sh2[c];
        float vv[4] = {val.x, val.y, val.z, val.w};
        for (int j = 0; j < 4; ++j) {
            float u1 = vv[j] + fA;
            float u2 = vv[j] + fB;
            s1[hw4 + j][c] = (u1 > 0.f) ? 1 : ((u1 < 0.f) ? -1 : 0);
            s2[hw4 + j][c] = (u2 > 0.f) ? 1 : ((u2 < 0.f) ? -1 : 0);
        }
    }
    __syncthreads();
    int c4 = (t & 63) * 4;
    for (int j = 0; j < 8; ++j) {
        int hwl = (t >> 6) + 4 * j;
        int hwg = hw0 + hwl;
        int h = hwg / WID, w = hwg - h * WID;
        uchar4 p1 = *(const uchar4*)&s1[hwl][c4];
        uchar4 p2 = *(const uchar4*)&s2[hwl][c4];
        size_t dst = ((size_t)(b * PIMG) + (size_t)(h + 1) * PW + (w + 1)) * 256 + c4;
        *(uchar4*)(a1 + dst) = p1;
        *(uchar4*)(a2 + dst) = p2;
    }
}

// ---------------- binarized implicit-GEMM conv ----------------
// M = NPIX, N = 256, K = 2304 (dual activation streams share B).
// Groups of 2 k64-steps per barrier (32 MFMAs/wave between barriers).
// B: global_load_lds into double-buffered 8KB LDS groups, source-side
//    swizzle kk=(cs-(row>>1))&3 (round-4-verified: 0 bank conflicts).
// A: direct per-lane global v4i loads, register-pipelined 2 steps ahead
//    into the just-consumed slot (single-buffered: round-1 showed the
//    double-buffered variant + launch_bounds(256,6) spills to scratch,
//    VGPR 40 + 6.9 GB HBM traffic).
// Barrier discipline (T3/T4): raw s_barrier + counted s_waitcnt vmcnt(8)
//    — only the 2 B global_load_lds (oldest in the FIFO vmcnt queue)
//    must land before the LDS buffer swap; the 8 A register loads stay
//    in flight across the barrier. Their consumers are next group's
//    MFMAs, for which the compiler inserts its own counted waits.
//    sched_barrier(0) after the B stages keeps them oldest so the
//    literal vmcnt count stays valid.
// K-step order s = dh*12 + k4*3 + dw (dw innermost -> L1 reuse of A rows).
template<int SB>
__global__ __launch_bounds__(256, 3)
void bingemm(const int8_t* __restrict__ a1g,
             const int8_t* __restrict__ a2g,
             const int8_t* __restrict__ wp,
             const float* __restrict__ params,
             const void* __restrict__ res,
             void* __restrict__ outp,
             const float* __restrict__ shA,
             const float* __restrict__ shB,
             int8_t* __restrict__ o1g,
             int8_t* __restrict__ o2g)
{
    __shared__ __align__(16) int8_t sB[2][8192];   // [buf][sub*4096 + row*64 + cs*16]

    // XCD-aware decode: each XCD owns a contiguous 1/8 M-slice (4 images)
    int fid = blockIdx.x;                 // 0..3135
    int xcd = fid & 7, slot = fid >> 3;   // slot 0..391
    int o0 = (slot & 3) * 64;
    int m0 = (xcd * 98 + (slot >> 2)) * 128;

    int t = threadIdx.x, lane = t & 63, wv = t >> 6;
    int ml = lane & 15, kc = lane >> 4;

    // per-lane A pixel byte offsets (padded NHWC), 2 M-slices
    int apix[2];
    #pragma unroll
    for (int ms = 0; ms < 2; ++ms) {
        int pix = m0 + wv * 32 + ms * 16 + ml;
        int b = pix / HWSZ, hw = pix - b * HWSZ;
        int h = hw / WID, w = hw - h * WID;
        apix[ms] = (b * PIMG + (h + 1) * PW + (w + 1)) * 256 + kc * 16;
    }
    // B staging: thread t fills LDS slot t (16B) of each 4KB sub-tile.
    // slot: row = t>>2, chunk-slot cs = t&3; source chunk kk = (cs-(row>>1))&3
    int brow = t >> 2, bcs = t & 3;
    int bkk = (bcs - (brow >> 1)) & 3;
    const int8_t* bsrc = wp + (size_t)(o0 + brow) * KTOT + (size_t)bkk * 16;
    // per-lane swizzled B read base: row=ns*16+ml, cs=(kc+(ml>>1))&3
    int rbase = ml * 64 + (((kc + (ml >> 1)) & 3) * 16);

    v4i acc1[2][4], acc2[2][4];
    #pragma unroll
    for (int i = 0; i < 2; ++i)
        #pragma unroll
        for (int n = 0; n < 4; ++n) {
            acc1[i][n] = (v4i){0, 0, 0, 0};
            acc2[i][n] = (v4i){0, 0, 0, 0};
        }

    v4i a1f[2][2], a2f[2][2];   // [step&1][ms]

    // step s -> (dh, k4, dw): s = dh*12 + k4*3 + dw
    #define AOFF(s) ((((s)/12 - 1) * PW + ((s)%3 - 1)) * 256 + (((s)%12)/3) * 64)
    #define KOFF(s) ((((s)/12) * 3 + (s)%3) * 256 + (((s)%12)/3) * 64)

    // prologue: stage group 0 (steps 0,1)
    load_lds_16(bsrc + KOFF(0), &sB[0][0 * 4096 + wv * 1024]);
    load_lds_16(bsrc + KOFF(1), &sB[0][1 * 4096 + wv * 1024]);
    __builtin_amdgcn_sched_barrier(0);   // keep B stages oldest in vmcnt queue
    a1f[0][0] = *(const v4i*)(a1g + apix[0] + AOFF(0));
    a1f[0][1] = *(const v4i*)(a1g + apix[1] + AOFF(0));
    a2f[0][0] = *(const v4i*)(a2g + apix[0] + AOFF(0));
    a2f[0][1] = *(const v4i*)(a2g + apix[1] + AOFF(0));
    a1f[1][0] = *(const v4i*)(a1g + apix[0] + AOFF(1));
    a1f[1][1] = *(const v4i*)(a1g + apix[1] + AOFF(1));
    a2f[1][0] = *(const v4i*)(a2g + apix[0] + AOFF(1));
    a2f[1][1] = *(const v4i*)(a2g + apix[1] + AOFF(1));
    __builtin_amdgcn_sched_barrier(0);
    asm volatile("s_waitcnt vmcnt(8)");
    __builtin_amdgcn_s_barrier();
    __builtin_amdgcn_sched_barrier(0);

    #pragma unroll
    for (int g = 0; g < 18; ++g) {
        int gb = g & 1;
        // prefetch next group's B into the other LDS buffer
        if (g < 17) {
            load_lds_16(bsrc + KOFF(2 * g + 2), &sB[gb ^ 1][0 * 4096 + wv * 1024]);
            load_lds_16(bsrc + KOFF(2 * g + 3), &sB[gb ^ 1][1 * 4096 + wv * 1024]);
            __builtin_amdgcn_sched_barrier(0);  // B stages stay oldest in queue
        }
        #pragma unroll
        for (int j = 0; j < 2; ++j) {
            int s = 2 * g + j;
            v4i bf[4];
            #pragma unroll
            for (int ns = 0; ns < 4; ++ns)
                bf[ns] = *(const v4i*)&sB[gb][j * 4096 + ns * 1024 + rbase];
            #pragma unroll
            for (int ms = 0; ms < 2; ++ms)
                #pragma unroll
                for (int ns = 0; ns < 4; ++ns) {
                    acc1[ms][ns] = __builtin_amdgcn_mfma_i32_16x16x64_i8(a1f[j][ms], bf[ns], acc1[ms][ns], 0, 0, 0);
                    acc2[ms][ns] = __builtin_amdgcn_mfma_i32_16x16x64_i8(a2f[j][ms], bf[ns], acc2[ms][ns], 0, 0, 0);
                }
            // prefetch A for step s+2 (consumed next group; stays in flight
            // across the counted barrier)
            if (g < 17) {
                int sn = s + 2;
                a1f[j][0] = *(const v4i*)(a1g + apix[0] + AOFF(sn));
                a1f[j][1] = *(const v4i*)(a1g + apix[1] + AOFF(sn));
                a2f[j][0] = *(const v4i*)(a2g + apix[0] + AOFF(sn));
                a2f[j][1] = *(const v4i*)(a2g + apix[1] + AOFF(sn));
            }
        }
        if (g < 17) {
            // counted drain: only the 2 B stages (oldest) must have landed;
            // the 8 A loads remain in flight across the barrier.
            __builtin_amdgcn_sched_barrier(0);
            asm volatile("s_waitcnt vmcnt(8)");
            __builtin_amdgcn_s_barrier();
            __builtin_amdgcn_sched_barrier(0);
        }
    }
    #undef AOFF
    #undef KOFF

    // --- epilogue: D layout col(n)=lane&15, row(m)=(lane>>4)*4+r ---
    #pragma unroll
    for (int ns = 0; ns < 4; ++ns) {
        int o = o0 + ns * 16 + ml;
        float c1 = params[o], c2 = params[256 + o], c3 = params[512 + o];
        float sA = 0.f, sBv = 0.f;
        if (SB == 1) { sA = shA[o]; sBv = shB[o]; }
        #pragma unroll
        for (int ms = 0; ms < 2; ++ms) {
            int pix0 = m0 + wv * 32 + ms * 16 + kc * 4;
            int b = pix0 / HWSZ, hw = pix0 - b * HWSZ;
            size_t rb = ((size_t)(b * CCH + o)) * HWSZ + hw;
            float rv[4];
            if (SB == 1) {
                float4 r4 = *(const float4*)((const float*)res + rb);
                rv[0] = r4.x; rv[1] = r4.y; rv[2] = r4.z; rv[3] = r4.w;
            } else {
                ushort4 u = *(const ushort4*)((const uint16_t*)res + rb);
                rv[0] = __uint_as_float((uint32_t)u.x << 16);
                rv[1] = __uint_as_float((uint32_t)u.y << 16);
                rv[2] = __uint_as_float((uint32_t)u.z << 16);
                rv[3] = __uint_as_float((uint32_t)u.w << 16);
            }
            float vals[4];
            #pragma unroll
            for (int r = 0; r < 4; ++r) {
                float v = (float)acc1[ms][ns][r] * c1
                        + (float)acc2[ms][ns][r] * c2 + c3 + rv[r];
                vals[r] = fminf(1.f, fmaxf(-1.f, v));
            }
            if (SB == 1) {
                ushort4 st;
                st.x = f2bf(vals[0]); st.y = f2bf(vals[1]);
                st.z = f2bf(vals[2]); st.w = f2bf(vals[3]);
                *(ushort4*)((uint16_t*)outp + rb) = st;
                int h = hw / WID, w = hw - h * WID;
                size_t pp = ((size_t)(b * PIMG) + (size_t)(h + 1) * PW + (w + 1)) * 256 + o;
                #pragma unroll
                for (int r = 0; r < 4; ++r) {
                    float u1 = vals[r] + sA, u2 = vals[r] + sBv;
                    o1g[pp + (size_t)r * 256] = (u1 > 0.f) ? 1 : ((u1 < 0.f) ? -1 : 0);
                    o2g[pp + (size_t)r * 256] = (u2 > 0.f) ? 1 : ((u2 < 0.f) ? -1 : 0);
                }
            } else {
                float4 st = {vals[0], vals[1], vals[2], vals[3]};
                *(float4*)((float*)outp + rb) = st;
            }
        }
    }
}

extern "C" void kernel_launch(void* const* d_in, const int* in_sizes, int n_in,
                              void* d_out, int out_size, void* d_ws, size_t ws_size,
                              hipStream_t stream) {
    const float* x    = (const float*)d_in[0];
    const float* sh11 = (const float*)d_in[1];
    const float* sh12 = (const float*)d_in[2];
    const float* w1   = (const float*)d_in[3];
    const float* sc1  = (const float*)d_in[4];
    const float* g1   = (const float*)d_in[5];
    const float* b1p  = (const float*)d_in[6];
    const float* m1   = (const float*)d_in[7];
    const float* v1   = (const float*)d_in[8];
    const float* sh21 = (const float*)d_in[9];
    const float* sh22 = (const float*)d_in[10];
    const float* w2   = (const float*)d_in[11];
    const float* sc2  = (const float*)d_in[12];
    const float* g2   = (const float*)d_in[13];
    const float* b2p  = (const float*)d_in[14];
    const float* m2   = (const float*)d_in[15];
    const float* v2   = (const float*)d_in[16];

    uint8_t* ws = (uint8_t*)d_ws;
    size_t off = 0;
    auto alloc = [&](size_t bytes) -> uint8_t* {
        uint8_t* p = ws + off;
        off += (bytes + 255) & ~(size_t)255;
        return p;
    };
    const size_t PADB = (size_t)BAT * PIMG * 256;   // 27.56 MB
    int8_t*   a1  = (int8_t*)alloc(PADB);
    int8_t*   a2  = (int8_t*)alloc(PADB);
    int8_t*   bb1 = (int8_t*)alloc(PADB);
    int8_t*   bb2 = (int8_t*)alloc(PADB);
    uint16_t* mid = (uint16_t*)alloc((size_t)NPIX * 256 * 2);  // bf16 NCHW
    int8_t*   wp1 = (int8_t*)alloc((size_t)256 * KTOT);
    int8_t*   wp2 = (int8_t*)alloc((size_t)256 * KTOT);
    float*    par1 = (float*)alloc(3 * 256 * 4);
    float*    par2 = (float*)alloc(3 * 256 * 4);
    (void)ws_size; (void)in_sizes; (void)n_in; (void)out_size;

    pack_weights<<<256, 256, 0, stream>>>(w1, sc1, g1, b1p, m1, v1, wp1, par1);
    pack_weights<<<256, 256, 0, stream>>>(w2, sc2, g2, b2p, m2, v2, wp2, par2);
    halo_zero<<<128, 256, 0, stream>>>(a1, a2, bb1, bb2);
    binarize_x<<<dim3(98, 32), 256, 0, stream>>>(x, sh11, sh12, a1, a2);
    bingemm<1><<<3136, 256, 0, stream>>>(a1, a2, wp1, par1, x, mid,
                                         sh21, sh22, bb1, bb2);
    bingemm<2><<<3136, 256, 0, stream>>>(bb1, bb2, wp2, par2, mid, d_out,
                                         nullptr, nullptr, nullptr, nullptr);
}

// Round 3
// 543.681 us; speedup vs baseline: 5.8539x; 1.3369x over previous
//
#include <hip/hip_runtime.h>
#include <cstdint>
#include <cstddef>

typedef int v4i __attribute__((ext_vector_type(4)));

#define HWSZ 3136
#define WID 56
#define CCH 256
#define BAT 32
#define NPIX (BAT*HWSZ)   /* 100352 */
#define KTOT 2304
#define PW 58
#define PIMG (PW*PW)      /* 3364 */
/* activation plane layout: [k4 plane][b][pix][64B], 4 planes per buffer */
#define PSZ (BAT*PIMG*64) /* 6889472 bytes per plane */

static __device__ __forceinline__ uint16_t f2bf(float f) {
    uint32_t x = __float_as_uint(f);
    x += 0x7fffu + ((x >> 16) & 1u);
    return (uint16_t)(x >> 16);
}

static __device__ __forceinline__ void load_lds_16(const void* g, void* l) {
    __builtin_amdgcn_global_load_lds(
        (const __attribute__((address_space(1))) uint32_t*)g,
        (__attribute__((address_space(3))) uint32_t*)l, 16, 0, 0);
}

// ---------------- pack weights + fused epilogue params ----------------
__global__ void pack_weights(const float* __restrict__ w,
                             const float* __restrict__ sc,
                             const float* __restrict__ g,
                             const float* __restrict__ bb,
                             const float* __restrict__ m,
                             const float* __restrict__ v,
                             int8_t* __restrict__ wpack,
                             float* __restrict__ params) {
    int o = blockIdx.x;
    int t = threadIdx.x;
    const float* wo = w + (size_t)o * KTOT;
    __shared__ float red[256];
    float s = 0.f;
    for (int i = t; i < KTOT; i += 256) {
        float val = wo[i];            // i = c*9 + tap
        s += fabsf(val);
        int c = i / 9, tap = i - c * 9;
        int8_t sgn = (val > 0.f) ? 1 : ((val < 0.f) ? -1 : 0);
        wpack[(size_t)o * KTOT + tap * 256 + c] = sgn;
    }
    red[t] = s;
    __syncthreads();
    for (int off = 128; off > 0; off >>= 1) {
        if (t < off) red[t] += red[t + off];
        __syncthreads();
    }
    if (t == 0) {
        float alpha = red[0] / (float)KTOT;
        float inv = rsqrtf(v[o] + 1e-5f);
        float cs = alpha * inv * g[o];
        params[o]         = cs;
        params[256 + o]   = cs * sc[o];
        params[512 + o]   = bb[o] - m[o] * inv * g[o];
    }
}

// ---------------- zero halos of 4 padded activation buffers (plane layout) --
__global__ void halo_zero(int8_t* b0, int8_t* b1, int8_t* b2, int8_t* b3) {
    int bx = blockIdx.x;                  // 0..127 : buf = bx>>5, img = bx&31
    int8_t* bufs[4] = {b0, b1, b2, b3};
    int8_t* buf = bufs[bx >> 5];
    int im = bx & 31;
    v4i z = (v4i){0, 0, 0, 0};
    // 4 planes x 228 halo pixels x 4 x 16B = 3648 chunks
    for (int idx = threadIdx.x; idx < 3648; idx += 256) {
        int plane = idx / 912;
        int rr = idx - plane * 912;
        int pix_i = rr >> 2, c16 = rr & 3;
        int h, w;
        if (pix_i < 58)       { h = 0;  w = pix_i; }
        else if (pix_i < 116) { h = 57; w = pix_i - 58; }
        else if (pix_i < 172) { h = pix_i - 115; w = 0; }   // h=1..56
        else                  { h = pix_i - 171; w = 57; }  // h=1..56
        size_t off = (size_t)plane * PSZ + (size_t)im * PIMG * 64
                   + (size_t)(h * PW + w) * 64 + c16 * 16;
        *(v4i*)(buf + off) = z;
    }
}

// ---------------- binarize x (NCHW fp32) -> a1,a2 (padded plane int8) -------
__global__ void binarize_x(const float* __restrict__ x,
                           const float* __restrict__ sh1,
                           const float* __restrict__ sh2,
                           int8_t* __restrict__ a1,
                           int8_t* __restrict__ a2) {
    __shared__ int8_t s1[32][260];
    __shared__ int8_t s2[32][260];
    int b = blockIdx.y;
    int hw0 = blockIdx.x * 32;
    int t = threadIdx.x;
    int hw4 = (t & 7) * 4;
    int crow = t >> 3;   // 0..31
    for (int i = 0; i < 8; ++i) {
        int c = crow + 32 * i;
        float4 val = *(const float4*)(x + ((size_t)(b * CCH + c)) * HWSZ + hw0 + hw4);
        float fA = sh1[c], fB = sh2[c];
        float vv[4] = {val.x, val.y, val.z, val.w};
        for (int j = 0; j < 4; ++j) {
            float u1 = vv[j] + fA;
            float u2 = vv[j] + fB;
            s1[hw4 + j][c] = (u1 > 0.f) ? 1 : ((u1 < 0.f) ? -1 : 0);
            s2[hw4 + j][c] = (u2 > 0.f) ? 1 : ((u2 < 0.f) ? -1 : 0);
        }
    }
    __syncthreads();
    int c4 = (t & 63) * 4;
    int plane = c4 >> 6, cin = c4 & 63;
    for (int j = 0; j < 8; ++j) {
        int hwl = (t >> 6) + 4 * j;
        int hwg = hw0 + hwl;
        int h = hwg / WID, w = hwg - h * WID;
        uchar4 p1 = *(const uchar4*)&s1[hwl][c4];
        uchar4 p2 = *(const uchar4*)&s2[hwl][c4];
        size_t dst = (size_t)plane * PSZ
                   + ((size_t)(b * PIMG) + (size_t)(h + 1) * PW + (w + 1)) * 64 + cin;
        *(uchar4*)(a1 + dst) = p1;
        *(uchar4*)(a2 + dst) = p2;
    }
}

// ---------------- binarized implicit-GEMM conv ----------------
// M = NPIX, N = 256, K = 2304 (dual activation streams share B).
// Groups of 2 k64-steps per barrier (32 MFMAs/wave between barriers).
// B: global_load_lds into double-buffered 8KB LDS groups, source-side
//    swizzle kk=(cs-(row>>1))&3 (verified: 0 bank conflicts).
// A: PLANE layout [k4][b][pix][64B] -> each per-lane v4i fragment load is a
//    single fully-contiguous 1KB wave burst (was 16 scattered 64B segments
//    in NHWC-256).  Register-pipelined 2 steps ahead into the just-consumed
//    slot (round-1: deeper buffering at tight launch_bounds spills).
// Barrier discipline: raw s_barrier + counted s_waitcnt vmcnt(8) -- only the
//    2 B global_load_lds (kept oldest in the FIFO vmcnt queue by
//    sched_barrier(0)) must land; the 8 A loads stay in flight across it.
// K-step order s = dh*12 + k4*3 + dw (dw innermost -> L1 reuse of A rows).
template<int SB>
__global__ __launch_bounds__(256, 3)
void bingemm(const int8_t* __restrict__ a1g,
             const int8_t* __restrict__ a2g,
             const int8_t* __restrict__ wp,
             const float* __restrict__ params,
             const void* __restrict__ res,
             void* __restrict__ outp,
             const float* __restrict__ shA,
             const float* __restrict__ shB,
             int8_t* __restrict__ o1g,
             int8_t* __restrict__ o2g)
{
    __shared__ __align__(16) int8_t sB[2][8192];   // [buf][sub*4096 + row*64 + cs*16]

    // XCD-aware decode: each XCD owns a contiguous 1/8 M-slice (4 images)
    int fid = blockIdx.x;                 // 0..3135
    int xcd = fid & 7, slot = fid >> 3;   // slot 0..391
    int o0 = (slot & 3) * 64;
    int m0 = (xcd * 98 + (slot >> 2)) * 128;

    int t = threadIdx.x, lane = t & 63, wv = t >> 6;
    int ml = lane & 15, kc = lane >> 4;

    // per-lane A pixel byte offsets (plane layout, plane added per-step)
    int apix[2];
    #pragma unroll
    for (int ms = 0; ms < 2; ++ms) {
        int pix = m0 + wv * 32 + ms * 16 + ml;
        int b = pix / HWSZ, hw = pix - b * HWSZ;
        int h = hw / WID, w = hw - h * WID;
        apix[ms] = (b * PIMG + (h + 1) * PW + (w + 1)) * 64 + kc * 16;
    }
    // B staging: thread t fills LDS slot t (16B) of each 4KB sub-tile.
    // slot: row = t>>2, chunk-slot cs = t&3; source chunk kk = (cs-(row>>1))&3
    int brow = t >> 2, bcs = t & 3;
    int bkk = (bcs - (brow >> 1)) & 3;
    const int8_t* bsrc = wp + (size_t)(o0 + brow) * KTOT + (size_t)bkk * 16;
    // per-lane swizzled B read base: row=ns*16+ml, cs=(kc+(ml>>1))&3
    int rbase = ml * 64 + (((kc + (ml >> 1)) & 3) * 16);

    v4i acc1[2][4], acc2[2][4];
    #pragma unroll
    for (int i = 0; i < 2; ++i)
        #pragma unroll
        for (int n = 0; n < 4; ++n) {
            acc1[i][n] = (v4i){0, 0, 0, 0};
            acc2[i][n] = (v4i){0, 0, 0, 0};
        }

    v4i a1f[2][2], a2f[2][2];   // [step&1][ms]

    // step s -> (dh, k4, dw): s = dh*12 + k4*3 + dw
    #define AOFF(s) ((((s)%12)/3) * PSZ + ((((s)/12 - 1) * PW) + ((s)%3 - 1)) * 64)
    #define KOFF(s) ((((s)/12) * 3 + (s)%3) * 256 + (((s)%12)/3) * 64)

    // prologue: stage group 0 (steps 0,1)
    load_lds_16(bsrc + KOFF(0), &sB[0][0 * 4096 + wv * 1024]);
    load_lds_16(bsrc + KOFF(1), &sB[0][1 * 4096 + wv * 1024]);
    __builtin_amdgcn_sched_barrier(0);   // keep B stages oldest in vmcnt queue
    a1f[0][0] = *(const v4i*)(a1g + apix[0] + AOFF(0));
    a1f[0][1] = *(const v4i*)(a1g + apix[1] + AOFF(0));
    a2f[0][0] = *(const v4i*)(a2g + apix[0] + AOFF(0));
    a2f[0][1] = *(const v4i*)(a2g + apix[1] + AOFF(0));
    a1f[1][0] = *(const v4i*)(a1g + apix[0] + AOFF(1));
    a1f[1][1] = *(const v4i*)(a1g + apix[1] + AOFF(1));
    a2f[1][0] = *(const v4i*)(a2g + apix[0] + AOFF(1));
    a2f[1][1] = *(const v4i*)(a2g + apix[1] + AOFF(1));
    __builtin_amdgcn_sched_barrier(0);
    asm volatile("s_waitcnt vmcnt(8)");
    __builtin_amdgcn_s_barrier();
    __builtin_amdgcn_sched_barrier(0);

    #pragma unroll
    for (int g = 0; g < 18; ++g) {
        int gb = g & 1;
        // prefetch next group's B into the other LDS buffer
        if (g < 17) {
            load_lds_16(bsrc + KOFF(2 * g + 2), &sB[gb ^ 1][0 * 4096 + wv * 1024]);
            load_lds_16(bsrc + KOFF(2 * g + 3), &sB[gb ^ 1][1 * 4096 + wv * 1024]);
            __builtin_amdgcn_sched_barrier(0);  // B stages stay oldest in queue
        }
        #pragma unroll
        for (int j = 0; j < 2; ++j) {
            int s = 2 * g + j;
            v4i bf[4];
            #pragma unroll
            for (int ns = 0; ns < 4; ++ns)
                bf[ns] = *(const v4i*)&sB[gb][j * 4096 + ns * 1024 + rbase];
            #pragma unroll
            for (int ms = 0; ms < 2; ++ms)
                #pragma unroll
                for (int ns = 0; ns < 4; ++ns) {
                    acc1[ms][ns] = __builtin_amdgcn_mfma_i32_16x16x64_i8(a1f[j][ms], bf[ns], acc1[ms][ns], 0, 0, 0);
                    acc2[ms][ns] = __builtin_amdgcn_mfma_i32_16x16x64_i8(a2f[j][ms], bf[ns], acc2[ms][ns], 0, 0, 0);
                }
            // prefetch A for step s+2 (consumed next group; stays in flight
            // across the counted barrier)
            if (g < 17) {
                int sn = s + 2;
                a1f[j][0] = *(const v4i*)(a1g + apix[0] + AOFF(sn));
                a1f[j][1] = *(const v4i*)(a1g + apix[1] + AOFF(sn));
                a2f[j][0] = *(const v4i*)(a2g + apix[0] + AOFF(sn));
                a2f[j][1] = *(const v4i*)(a2g + apix[1] + AOFF(sn));
            }
        }
        if (g < 17) {
            // counted drain: only the 2 B stages (oldest) must have landed;
            // the 8 A loads remain in flight across the barrier.
            __builtin_amdgcn_sched_barrier(0);
            asm volatile("s_waitcnt vmcnt(8)");
            __builtin_amdgcn_s_barrier();
            __builtin_amdgcn_sched_barrier(0);
        }
    }
    #undef AOFF
    #undef KOFF

    // --- epilogue: D layout col(n)=lane&15, row(m)=(lane>>4)*4+r ---
    #pragma unroll
    for (int ns = 0; ns < 4; ++ns) {
        int o = o0 + ns * 16 + ml;
        float c1 = params[o], c2 = params[256 + o], c3 = params[512 + o];
        float sA = 0.f, sBv = 0.f;
        if (SB == 1) { sA = shA[o]; sBv = shB[o]; }
        #pragma unroll
        for (int ms = 0; ms < 2; ++ms) {
            int pix0 = m0 + wv * 32 + ms * 16 + kc * 4;
            int b = pix0 / HWSZ, hw = pix0 - b * HWSZ;
            size_t rb = ((size_t)(b * CCH + o)) * HWSZ + hw;
            float rv[4];
            if (SB == 1) {
                float4 r4 = *(const float4*)((const float*)res + rb);
                rv[0] = r4.x; rv[1] = r4.y; rv[2] = r4.z; rv[3] = r4.w;
            } else {
                ushort4 u = *(const ushort4*)((const uint16_t*)res + rb);
                rv[0] = __uint_as_float((uint32_t)u.x << 16);
                rv[1] = __uint_as_float((uint32_t)u.y << 16);
                rv[2] = __uint_as_float((uint32_t)u.z << 16);
                rv[3] = __uint_as_float((uint32_t)u.w << 16);
            }
            float vals[4];
            #pragma unroll
            for (int r = 0; r < 4; ++r) {
                float v = (float)acc1[ms][ns][r] * c1
                        + (float)acc2[ms][ns][r] * c2 + c3 + rv[r];
                vals[r] = fminf(1.f, fmaxf(-1.f, v));
            }
            if (SB == 1) {
                ushort4 st;
                st.x = f2bf(vals[0]); st.y = f2bf(vals[1]);
                st.z = f2bf(vals[2]); st.w = f2bf(vals[3]);
                *(ushort4*)((uint16_t*)outp + rb) = st;
                int h = hw / WID, w = hw - h * WID;
                // plane layout: o in [o0,o0+64) -> plane o0>>6, channel o&63
                size_t pp = (size_t)(o0 >> 6) * PSZ
                          + ((size_t)(b * PIMG) + (size_t)(h + 1) * PW + (w + 1)) * 64
                          + (o & 63);
                #pragma unroll
                for (int r = 0; r < 4; ++r) {
                    float u1 = vals[r] + sA, u2 = vals[r] + sBv;
                    o1g[pp + (size_t)r * 64] = (u1 > 0.f) ? 1 : ((u1 < 0.f) ? -1 : 0);
                    o2g[pp + (size_t)r * 64] = (u2 > 0.f) ? 1 : ((u2 < 0.f) ? -1 : 0);
                }
            } else {
                float4 st = {vals[0], vals[1], vals[2], vals[3]};
                *(float4*)((float*)outp + rb) = st;
            }
        }
    }
}

extern "C" void kernel_launch(void* const* d_in, const int* in_sizes, int n_in,
                              void* d_out, int out_size, void* d_ws, size_t ws_size,
                              hipStream_t stream) {
    const float* x    = (const float*)d_in[0];
    const float* sh11 = (const float*)d_in[1];
    const float* sh12 = (const float*)d_in[2];
    const float* w1   = (const float*)d_in[3];
    const float* sc1  = (const float*)d_in[4];
    const float* g1   = (const float*)d_in[5];
    const float* b1p  = (const float*)d_in[6];
    const float* m1   = (const float*)d_in[7];
    const float* v1   = (const float*)d_in[8];
    const float* sh21 = (const float*)d_in[9];
    const float* sh22 = (const float*)d_in[10];
    const float* w2   = (const float*)d_in[11];
    const float* sc2  = (const float*)d_in[12];
    const float* g2   = (const float*)d_in[13];
    const float* b2p  = (const float*)d_in[14];
    const float* m2   = (const float*)d_in[15];
    const float* v2   = (const float*)d_in[16];

    uint8_t* ws = (uint8_t*)d_ws;
    size_t off = 0;
    auto alloc = [&](size_t bytes) -> uint8_t* {
        uint8_t* p = ws + off;
        off += (bytes + 255) & ~(size_t)255;
        return p;
    };
    const size_t PADB = (size_t)BAT * PIMG * 256;   // 27.56 MB (4 planes)
    int8_t*   a1  = (int8_t*)alloc(PADB);
    int8_t*   a2  = (int8_t*)alloc(PADB);
    int8_t*   bb1 = (int8_t*)alloc(PADB);
    int8_t*   bb2 = (int8_t*)alloc(PADB);
    uint16_t* mid = (uint16_t*)alloc((size_t)NPIX * 256 * 2);  // bf16 NCHW
    int8_t*   wp1 = (int8_t*)alloc((size_t)256 * KTOT);
    int8_t*   wp2 = (int8_t*)alloc((size_t)256 * KTOT);
    float*    par1 = (float*)alloc(3 * 256 * 4);
    float*    par2 = (float*)alloc(3 * 256 * 4);
    (void)ws_size; (void)in_sizes; (void)n_in; (void)out_size;

    pack_weights<<<256, 256, 0, stream>>>(w1, sc1, g1, b1p, m1, v1, wp1, par1);
    pack_weights<<<256, 256, 0, stream>>>(w2, sc2, g2, b2p, m2, v2, wp2, par2);
    halo_zero<<<128, 256, 0, stream>>>(a1, a2, bb1, bb2);
    binarize_x<<<dim3(98, 32), 256, 0, stream>>>(x, sh11, sh12, a1, a2);
    bingemm<1><<<3136, 256, 0, stream>>>(a1, a2, wp1, par1, x, mid,
                                         sh21, sh22, bb1, bb2);
    bingemm<2><<<3136, 256, 0, stream>>>(bb1, bb2, wp2, par2, mid, d_out,
                                         nullptr, nullptr, nullptr, nullptr);
}